// Round 6
// baseline (639.381 us; speedup 1.0000x reference)
//
#include <hip/hip_runtime.h>
#include <cstdint>

// Transformer encoder layer. bf16-MFMA GEMMs (256² + 128x256 geometries, counted-vmcnt
// 8-phase pipelines) + bf16-MFMA flash attention (2-phase K/V double-buffer).
// B=4 S=2048 D=1024 H=16 depth=64 DFF=4096.
//
// Workspace layout (MB offsets, total 168 MB):
//   [0,16)    qb bf16 [B,H,S,64]     -> attn_out fp32 [0,32) -> ffn fp32 [0,32)
//   [16,32)   kb bf16 [B,H,S,64]
//   [32,48)   vtb bf16 [B,H,64,S]    -> out1 fp32 [32,64)
//   [48,64)   ctxb bf16 [B,S,D]
//   [64,80)   xb bf16                -> out1b bf16
//   [80,144)  hbuf bf16 [8192,4096]
//   [144,150) wqkvt bf16 [3072,1024]
//   [150,152) wot bf16 [1024,1024]
//   [152,160) w1t bf16 [4096,1024]
//   [160,168) w2t bf16 [1024,4096]

#define BATCH 4
#define SEQ   2048
#define DM    1024
#define NH    16
#define DEPTH 64
#define DFF_  4096
#define EPSF  1e-6f

typedef short bf16x8 __attribute__((ext_vector_type(8)));
typedef float f32x4  __attribute__((ext_vector_type(4)));

__device__ __forceinline__ unsigned short f2bf(float f) {
  union { float f; unsigned int u; } v; v.f = f;
  unsigned int u = v.u;
  return (unsigned short)((u + 0x7fffu + ((u >> 16) & 1u)) >> 16);  // RNE
}

__device__ __forceinline__ void gload_lds16(const void* g, void* l) {
  __builtin_amdgcn_global_load_lds(
      (const __attribute__((address_space(1))) unsigned int*)g,
      (__attribute__((address_space(3))) unsigned int*)l, 16, 0, 0);
}

#define VMCNT(n) asm volatile("s_waitcnt vmcnt(" #n ")" ::: "memory")

// ---------------- 8-phase 256x256 bf16 MFMA GEMM (validated round 5) ----------------
// Used for FFN1 (M=8192, N=4096: 512 blocks, full fill).
template<int EPI>
__global__ __launch_bounds__(512, 2)
void gemm8(const unsigned short* __restrict__ A, const unsigned short* __restrict__ Bt,
           const float* __restrict__ bias0, const float* __restrict__ bias1,
           const float* __restrict__ bias2, float* __restrict__ Cf,
           unsigned short* __restrict__ Cb0, unsigned short* __restrict__ Cb1,
           unsigned short* __restrict__ Cb2, int M, int N, int K)
{
  __shared__ char smem[131072];
  const int tid  = threadIdx.x;
  const int lane = tid & 63;
  const int wid  = tid >> 6;
  const int wr   = wid >> 2;          // 0..1  (M half)
  const int wcn  = wid & 3;           // 0..3  (N quarter)
  const int fr   = lane & 15;
  const int kh   = lane >> 4;

  const int nbx  = N >> 8;
  const int nwg  = gridDim.x;
  const int flat = blockIdx.x;
  const int swz  = (flat & 7) * (nwg >> 3) + (flat >> 3);
  const int bx = swz % nbx, by = swz / nbx;
  const int m0 = by << 8, n0 = bx << 8;

  const int lr  = tid >> 3;
  const int ch  = tid & 7;
  const int sch = ch ^ (lr & 7);
  const char* gA = (const char*)A + ((size_t)(m0 + lr) * K) * 2 + sch * 16;
  const char* gB = (const char*)Bt + ((size_t)(n0 + lr) * K) * 2 + sch * 16;
  const size_t rstep = (size_t)K * 128;

  const int chk0 = ((kh) ^ (fr & 7)) * 16;
  const int chk1 = ((4 + kh) ^ (fr & 7)) * 16;
  const int rowA = wr * 128 + fr;
  const int rowB = wcn * 64 + fr;

  f32x4 acc[8][4] = {};
  bf16x8 bg[4][2];
  const int NT = K >> 6;

  {
    char* sb = smem;
    gload_lds16(gB + 0 * rstep, sb + 32768 + 0 * 8192 + tid * 16);
    gload_lds16(gB + 1 * rstep, sb + 32768 + 1 * 8192 + tid * 16);
    gload_lds16(gB + 2 * rstep, sb + 32768 + 2 * 8192 + tid * 16);
    gload_lds16(gB + 3 * rstep, sb + 32768 + 3 * 8192 + tid * 16);
    gload_lds16(gA + 0 * rstep, sb + 0 * 8192 + tid * 16);
    gload_lds16(gA + 2 * rstep, sb + 2 * 8192 + tid * 16);
    gload_lds16(gA + 1 * rstep, sb + 1 * 8192 + tid * 16);
    gload_lds16(gA + 3 * rstep, sb + 3 * 8192 + tid * 16);
    VMCNT(2);
    __builtin_amdgcn_s_barrier();
  }

  for (int t = 0; t < NT - 1; ++t) {
    char* rb = smem + ((t & 1) << 16);
    char* sb = smem + (((t + 1) & 1) << 16);
    const size_t kg = (size_t)(t + 1) * 128;
#pragma unroll
    for (int p = 0; p < 4; ++p) {
      if (p == 0) {
        gload_lds16(gB + kg + 0 * rstep, sb + 32768 + 0 * 8192 + tid * 16);
        gload_lds16(gB + kg + 1 * rstep, sb + 32768 + 1 * 8192 + tid * 16);
      } else if (p == 1) {
        gload_lds16(gB + kg + 2 * rstep, sb + 32768 + 2 * 8192 + tid * 16);
        gload_lds16(gB + kg + 3 * rstep, sb + 32768 + 3 * 8192 + tid * 16);
      } else if (p == 2) {
        gload_lds16(gA + kg + 0 * rstep, sb + 0 * 8192 + tid * 16);
        gload_lds16(gA + kg + 2 * rstep, sb + 2 * 8192 + tid * 16);
      } else {
        gload_lds16(gA + kg + 1 * rstep, sb + 1 * 8192 + tid * 16);
        gload_lds16(gA + kg + 3 * rstep, sb + 3 * 8192 + tid * 16);
      }
      if (p == 0) {
#pragma unroll
        for (int j = 0; j < 4; ++j) {
          bg[j][0] = *(const bf16x8*)(rb + 32768 + (rowB + j * 16) * 128 + chk0);
          bg[j][1] = *(const bf16x8*)(rb + 32768 + (rowB + j * 16) * 128 + chk1);
        }
      }
      bf16x8 a00 = *(const bf16x8*)(rb + (rowA + (2 * p) * 16) * 128 + chk0);
      bf16x8 a01 = *(const bf16x8*)(rb + (rowA + (2 * p) * 16) * 128 + chk1);
      bf16x8 a10 = *(const bf16x8*)(rb + (rowA + (2 * p + 1) * 16) * 128 + chk0);
      bf16x8 a11 = *(const bf16x8*)(rb + (rowA + (2 * p + 1) * 16) * 128 + chk1);
      __builtin_amdgcn_s_barrier();
      __builtin_amdgcn_s_setprio(1);
#pragma unroll
      for (int j = 0; j < 4; ++j) {
        acc[2*p][j]   = __builtin_amdgcn_mfma_f32_16x16x32_bf16(a00, bg[j][0], acc[2*p][j], 0, 0, 0);
        acc[2*p][j]   = __builtin_amdgcn_mfma_f32_16x16x32_bf16(a01, bg[j][1], acc[2*p][j], 0, 0, 0);
        acc[2*p+1][j] = __builtin_amdgcn_mfma_f32_16x16x32_bf16(a10, bg[j][0], acc[2*p+1][j], 0, 0, 0);
        acc[2*p+1][j] = __builtin_amdgcn_mfma_f32_16x16x32_bf16(a11, bg[j][1], acc[2*p+1][j], 0, 0, 0);
      }
      __builtin_amdgcn_s_setprio(0);
      if (p == 1) VMCNT(4);
      if (p == 3) VMCNT(2);
      __builtin_amdgcn_s_barrier();
    }
  }
  {
    char* rb = smem + (((NT - 1) & 1) << 16);
#pragma unroll
    for (int p = 0; p < 4; ++p) {
      if (p == 0) {
#pragma unroll
        for (int j = 0; j < 4; ++j) {
          bg[j][0] = *(const bf16x8*)(rb + 32768 + (rowB + j * 16) * 128 + chk0);
          bg[j][1] = *(const bf16x8*)(rb + 32768 + (rowB + j * 16) * 128 + chk1);
        }
      }
      bf16x8 a00 = *(const bf16x8*)(rb + (rowA + (2 * p) * 16) * 128 + chk0);
      bf16x8 a01 = *(const bf16x8*)(rb + (rowA + (2 * p) * 16) * 128 + chk1);
      bf16x8 a10 = *(const bf16x8*)(rb + (rowA + (2 * p + 1) * 16) * 128 + chk0);
      bf16x8 a11 = *(const bf16x8*)(rb + (rowA + (2 * p + 1) * 16) * 128 + chk1);
      __builtin_amdgcn_s_barrier();
      __builtin_amdgcn_s_setprio(1);
#pragma unroll
      for (int j = 0; j < 4; ++j) {
        acc[2*p][j]   = __builtin_amdgcn_mfma_f32_16x16x32_bf16(a00, bg[j][0], acc[2*p][j], 0, 0, 0);
        acc[2*p][j]   = __builtin_amdgcn_mfma_f32_16x16x32_bf16(a01, bg[j][1], acc[2*p][j], 0, 0, 0);
        acc[2*p+1][j] = __builtin_amdgcn_mfma_f32_16x16x32_bf16(a10, bg[j][0], acc[2*p+1][j], 0, 0, 0);
        acc[2*p+1][j] = __builtin_amdgcn_mfma_f32_16x16x32_bf16(a11, bg[j][1], acc[2*p+1][j], 0, 0, 0);
      }
      __builtin_amdgcn_s_setprio(0);
      if (p == 1) VMCNT(0);
      __builtin_amdgcn_s_barrier();
    }
  }

  if (EPI == 2) {
    const int seg = n0 >> 10;
    const float* bp = seg == 0 ? bias0 : (seg == 1 ? bias1 : bias2);
    unsigned short* dst = seg == 0 ? Cb0 : (seg == 1 ? Cb1 : Cb2);
    float bc[4];
#pragma unroll
    for (int j = 0; j < 4; ++j) bc[j] = bp[(n0 & 1023) + wcn * 64 + j * 16 + fr];
#pragma unroll
    for (int m = 0; m < 8; ++m)
#pragma unroll
      for (int jj = 0; jj < 4; ++jj) {
        const int row = m0 + wr * 128 + m * 16 + kh * 4 + jj;
        const int b = row >> 11, s = row & (SEQ - 1);
#pragma unroll
        for (int j = 0; j < 4; ++j) {
          const int cs = (n0 & 1023) + wcn * 64 + j * 16 + fr;
          const int hh = cs >> 6, d = cs & 63;
          const float v = acc[m][j][jj] + bc[j];
          if (seg < 2)
            dst[(((size_t)(b * NH + hh)) * SEQ + s) * DEPTH + d] = f2bf(v);
          else
            dst[(((size_t)(b * NH + hh)) * DEPTH + d) * SEQ + s] = f2bf(v);
        }
      }
  } else {
    float bc[4];
#pragma unroll
    for (int j = 0; j < 4; ++j) bc[j] = bias0[n0 + wcn * 64 + j * 16 + fr];
#pragma unroll
    for (int m = 0; m < 8; ++m)
#pragma unroll
      for (int jj = 0; jj < 4; ++jj) {
        const int row = m0 + wr * 128 + m * 16 + kh * 4 + jj;
#pragma unroll
        for (int j = 0; j < 4; ++j) {
          const int col = n0 + wcn * 64 + j * 16 + fr;
          float v = acc[m][j][jj] + bc[j];
          if (EPI == 1) {
            v = fmaxf(v, 0.f);
            Cb0[(size_t)row * N + col] = f2bf(v);
          } else {
            Cf[(size_t)row * N + col] = v;
          }
        }
      }
  }
}

// ---------------- 8-phase 128x256 bf16 MFMA GEMM (grid-fill geometry) ----------------
// 512 thr = 8 waves, 1M x 8N; wave tile 128x32 (acc 8x2). BK=64. LDS 2 x 48 KiB.
// Regions/K-tile: B0..B3 (rows n0+b*64), A0,A1 (rows m0+a*64). A reads progress through
// rows over phases (p0/p1 in A0, p2/p3 in A1) so A1 staging defers past the tile edge:
// stage B0B1|B2B3|A0|A1 over p0..p3; vmcnt(4) @p1-end (retire A1 of tile t),
// vmcnt(1) @p3-end (retire B*,A0 of t+1; keep A1(t+1) in flight). Never drain-0 in loop.
// EPI: 0 = fp32 [M,N] + bias; 2 = fused QKV scatter (q/k split-head, v transposed).
template<int EPI>
__global__ __launch_bounds__(512, 2)
void gemm128(const unsigned short* __restrict__ A, const unsigned short* __restrict__ Bt,
             const float* __restrict__ bias0, const float* __restrict__ bias1,
             const float* __restrict__ bias2, float* __restrict__ Cf,
             unsigned short* __restrict__ Cb0, unsigned short* __restrict__ Cb1,
             unsigned short* __restrict__ Cb2, int M, int N, int K)
{
  __shared__ char smem[98304];
  const int tid  = threadIdx.x;
  const int lane = tid & 63;
  const int wid  = tid >> 6;          // 0..7 = N strip
  const int fr   = lane & 15;
  const int kh   = lane >> 4;

  const int nbx  = N >> 8;
  const int nwg  = gridDim.x;
  const int flat = blockIdx.x;
  const int swz  = (flat & 7) * (nwg >> 3) + (flat >> 3);
  const int bx = swz % nbx, by = swz / nbx;
  const int m0 = by << 7, n0 = bx << 8;

  const int lr  = tid >> 3;
  const int sch = (tid & 7) ^ (lr & 7);
  const char* gA = (const char*)A + ((size_t)(m0 + lr) * K) * 2 + sch * 16;
  const char* gB = (const char*)Bt + ((size_t)(n0 + lr) * K) * 2 + sch * 16;
  const size_t rstep = (size_t)K * 128;

  const int chk0 = ((kh) ^ (fr & 7)) * 16;
  const int chk1 = ((4 + kh) ^ (fr & 7)) * 16;
  const int rowB = wid * 32 + fr;     // within B block rows [0,256)

  f32x4 acc[8][2] = {};
  bf16x8 bg[2][2];
  const int NT = K >> 6;

  // prologue: B0 B1 B2 B3 A0 A1; keep A1 in flight (needed only from p2)
  {
    char* sb = smem;
    gload_lds16(gB + 0 * rstep, sb + 16384 + 0 * 8192 + tid * 16);
    gload_lds16(gB + 1 * rstep, sb + 16384 + 1 * 8192 + tid * 16);
    gload_lds16(gB + 2 * rstep, sb + 16384 + 2 * 8192 + tid * 16);
    gload_lds16(gB + 3 * rstep, sb + 16384 + 3 * 8192 + tid * 16);
    gload_lds16(gA + 0 * rstep, sb + 0 * 8192 + tid * 16);
    gload_lds16(gA + 1 * rstep, sb + 1 * 8192 + tid * 16);
    VMCNT(1);
    __builtin_amdgcn_s_barrier();
  }

  for (int t = 0; t < NT - 1; ++t) {
    char* rb = smem + (t & 1) * 49152;
    char* sb = smem + ((t + 1) & 1) * 49152;
    const size_t kg = (size_t)(t + 1) * 128;
#pragma unroll
    for (int p = 0; p < 4; ++p) {
      if (p == 0) {
        gload_lds16(gB + kg + 0 * rstep, sb + 16384 + 0 * 8192 + tid * 16);
        gload_lds16(gB + kg + 1 * rstep, sb + 16384 + 1 * 8192 + tid * 16);
      } else if (p == 1) {
        gload_lds16(gB + kg + 2 * rstep, sb + 16384 + 2 * 8192 + tid * 16);
        gload_lds16(gB + kg + 3 * rstep, sb + 16384 + 3 * 8192 + tid * 16);
      } else if (p == 2) {
        gload_lds16(gA + kg + 0 * rstep, sb + 0 * 8192 + tid * 16);
      } else {
        gload_lds16(gA + kg + 1 * rstep, sb + 1 * 8192 + tid * 16);
      }
      if (p == 0) {
#pragma unroll
        for (int j = 0; j < 2; ++j) {
          bg[j][0] = *(const bf16x8*)(rb + 16384 + (rowB + j * 16) * 128 + chk0);
          bg[j][1] = *(const bf16x8*)(rb + 16384 + (rowB + j * 16) * 128 + chk1);
        }
      }
      bf16x8 a00 = *(const bf16x8*)(rb + ((2 * p) * 16 + fr) * 128 + chk0);
      bf16x8 a01 = *(const bf16x8*)(rb + ((2 * p) * 16 + fr) * 128 + chk1);
      bf16x8 a10 = *(const bf16x8*)(rb + ((2 * p + 1) * 16 + fr) * 128 + chk0);
      bf16x8 a11 = *(const bf16x8*)(rb + ((2 * p + 1) * 16 + fr) * 128 + chk1);
      __builtin_amdgcn_s_barrier();
      __builtin_amdgcn_s_setprio(1);
#pragma unroll
      for (int j = 0; j < 2; ++j) {
        acc[2*p][j]   = __builtin_amdgcn_mfma_f32_16x16x32_bf16(a00, bg[j][0], acc[2*p][j], 0, 0, 0);
        acc[2*p][j]   = __builtin_amdgcn_mfma_f32_16x16x32_bf16(a01, bg[j][1], acc[2*p][j], 0, 0, 0);
        acc[2*p+1][j] = __builtin_amdgcn_mfma_f32_16x16x32_bf16(a10, bg[j][0], acc[2*p+1][j], 0, 0, 0);
        acc[2*p+1][j] = __builtin_amdgcn_mfma_f32_16x16x32_bf16(a11, bg[j][1], acc[2*p+1][j], 0, 0, 0);
      }
      __builtin_amdgcn_s_setprio(0);
      if (p == 1) VMCNT(4);
      if (p == 3) VMCNT(1);
      __builtin_amdgcn_s_barrier();
    }
  }
  // final tile
  {
    char* rb = smem + ((NT - 1) & 1) * 49152;
#pragma unroll
    for (int p = 0; p < 4; ++p) {
      if (p == 0) {
#pragma unroll
        for (int j = 0; j < 2; ++j) {
          bg[j][0] = *(const bf16x8*)(rb + 16384 + (rowB + j * 16) * 128 + chk0);
          bg[j][1] = *(const bf16x8*)(rb + 16384 + (rowB + j * 16) * 128 + chk1);
        }
      }
      bf16x8 a00 = *(const bf16x8*)(rb + ((2 * p) * 16 + fr) * 128 + chk0);
      bf16x8 a01 = *(const bf16x8*)(rb + ((2 * p) * 16 + fr) * 128 + chk1);
      bf16x8 a10 = *(const bf16x8*)(rb + ((2 * p + 1) * 16 + fr) * 128 + chk0);
      bf16x8 a11 = *(const bf16x8*)(rb + ((2 * p + 1) * 16 + fr) * 128 + chk1);
      __builtin_amdgcn_s_barrier();
      __builtin_amdgcn_s_setprio(1);
#pragma unroll
      for (int j = 0; j < 2; ++j) {
        acc[2*p][j]   = __builtin_amdgcn_mfma_f32_16x16x32_bf16(a00, bg[j][0], acc[2*p][j], 0, 0, 0);
        acc[2*p][j]   = __builtin_amdgcn_mfma_f32_16x16x32_bf16(a01, bg[j][1], acc[2*p][j], 0, 0, 0);
        acc[2*p+1][j] = __builtin_amdgcn_mfma_f32_16x16x32_bf16(a10, bg[j][0], acc[2*p+1][j], 0, 0, 0);
        acc[2*p+1][j] = __builtin_amdgcn_mfma_f32_16x16x32_bf16(a11, bg[j][1], acc[2*p+1][j], 0, 0, 0);
      }
      __builtin_amdgcn_s_setprio(0);
      if (p == 1) VMCNT(0);
      __builtin_amdgcn_s_barrier();
    }
  }

  if (EPI == 2) {
    const int seg = n0 >> 10;
    const float* bp = seg == 0 ? bias0 : (seg == 1 ? bias1 : bias2);
    unsigned short* dst = seg == 0 ? Cb0 : (seg == 1 ? Cb1 : Cb2);
    float bc[2];
#pragma unroll
    for (int j = 0; j < 2; ++j) bc[j] = bp[(n0 & 1023) + wid * 32 + j * 16 + fr];
#pragma unroll
    for (int m = 0; m < 8; ++m)
#pragma unroll
      for (int jj = 0; jj < 4; ++jj) {
        const int row = m0 + m * 16 + kh * 4 + jj;
        const int b = row >> 11, s = row & (SEQ - 1);
#pragma unroll
        for (int j = 0; j < 2; ++j) {
          const int cs = (n0 & 1023) + wid * 32 + j * 16 + fr;
          const int hh = cs >> 6, d = cs & 63;
          const float v = acc[m][j][jj] + bc[j];
          if (seg < 2)
            dst[(((size_t)(b * NH + hh)) * SEQ + s) * DEPTH + d] = f2bf(v);
          else
            dst[(((size_t)(b * NH + hh)) * DEPTH + d) * SEQ + s] = f2bf(v);
        }
      }
  } else {
    float bc[2];
#pragma unroll
    for (int j = 0; j < 2; ++j) bc[j] = bias0[n0 + wid * 32 + j * 16 + fr];
#pragma unroll
    for (int m = 0; m < 8; ++m)
#pragma unroll
      for (int jj = 0; jj < 4; ++jj) {
        const int row = m0 + m * 16 + kh * 4 + jj;
#pragma unroll
        for (int j = 0; j < 2; ++j) {
          const int col = n0 + wid * 32 + j * 16 + fr;
          Cf[(size_t)row * N + col] = acc[m][j][jj] + bc[j];
        }
      }
  }
}

// ---------------- weight fp32 [K,N] -> bf16 [N,K] transpose ----------------
__global__ __launch_bounds__(256)
void transpose_to_bf16(const float* __restrict__ W, unsigned short* __restrict__ Wt,
                       int K, int N)
{
  __shared__ float t[32][33];
  const int tx = threadIdx.x & 31;
  const int ty = threadIdx.x >> 5;
  const int n0 = blockIdx.x * 32;
  const int k0 = blockIdx.y * 32;
#pragma unroll
  for (int i = 0; i < 4; ++i) {
    int r = ty + i * 8;
    t[r][tx] = W[(size_t)(k0 + r) * N + n0 + tx];
  }
  __syncthreads();
#pragma unroll
  for (int i = 0; i < 4; ++i) {
    int r = ty + i * 8;
    Wt[(size_t)(n0 + r) * K + k0 + tx] = f2bf(t[tx][r]);
  }
}

// ---------------- fp32 -> bf16 elementwise ----------------
__global__ __launch_bounds__(256)
void convert_bf16(const float* __restrict__ X, unsigned short* __restrict__ Xb, int n4)
{
  int i = blockIdx.x * 256 + threadIdx.x;
  if (i < n4) {
    float4 v = ((const float4*)X)[i];
    ushort4 r;
    r.x = f2bf(v.x); r.y = f2bf(v.y); r.z = f2bf(v.z); r.w = f2bf(v.w);
    ((ushort4*)Xb)[i] = r;
  }
}

// ---------------- bf16 MFMA flash attention, 2-phase K/V double-buffer ----------------
// Q,K: [B,H,S,64] bf16; Vt: [B,H,64,S] bf16; ctx out: [B,S,D] bf16.
// Grid (S/64, B*H), 256 thr (4 waves x 16 q-rows). KV tile = 64, double-buffered:
// stage tile t+1 BEFORE computing tile t; vmcnt(0)+s_barrier once per tile (T3 minimum).
// Softmax in log2 domain (v_exp_f32 = 2^x); mask premultiplied by -1e9*log2e at staging.
__global__ __launch_bounds__(256)
void attn_mfma(const unsigned short* __restrict__ Qb, const unsigned short* __restrict__ Kb,
               const unsigned short* __restrict__ Vtb, const float* __restrict__ mask,
               unsigned short* __restrict__ ctxb)
{
  __shared__ unsigned short Ks[2][64 * 64];
  __shared__ unsigned short Vts[2][64 * 64];
  __shared__ unsigned short Ps[4][16 * 72];
  __shared__ float Ms[SEQ];

  const int tid  = threadIdx.x;
  const int w    = tid >> 6;
  const int lane = tid & 63;
  const int fr   = lane & 15;
  const int kh   = lane >> 4;
  const int rbase = kh * 4;
  const int bh = blockIdx.y;
  const int b  = bh >> 4, hh = bh & 15;
  const int q0 = blockIdx.x * 64;

  const float MSCL = -1.0e9f * 1.44269504f;
  const float SSCL = 0.125f * 1.44269504f;

  for (int i = tid; i < SEQ / 4; i += 256) {
    float4 mv = *(const float4*)&mask[(size_t)b * SEQ + i * 4];
    mv.x *= MSCL; mv.y *= MSCL; mv.z *= MSCL; mv.w *= MSCL;
    *(float4*)&Ms[i * 4] = mv;
  }

  const size_t qrow = ((size_t)bh * SEQ + q0 + w * 16 + fr) * DEPTH;
  bf16x8 bq[2];
  bq[0] = *(const bf16x8*)(Qb + qrow + kh * 8);
  bq[1] = *(const bf16x8*)(Qb + qrow + 32 + kh * 8);

  float m_run = -1e30f, l_run = 0.f;
  f32x4 o[4] = {};

  const int stg_chunk = (lane & 7) ^ (lane >> 3);
  const int r8 = lane >> 3;
  unsigned short* Pw = &Ps[w][0];

  auto stage = [&](int buf, int kv) {
#pragma unroll
    for (int i = 0; i < 2; ++i) {
      int rr = w * 16 + i * 8 + r8;
      gload_lds16((const char*)Kb + (((size_t)bh * SEQ + kv + rr) * DEPTH) * 2 + stg_chunk * 16,
                  (char*)&Ks[buf][0] + (w * 16 + i * 8) * 128);
      gload_lds16((const char*)Vtb + (((size_t)bh * DEPTH + rr) * SEQ + kv) * 2 + stg_chunk * 16,
                  (char*)&Vts[buf][0] + (w * 16 + i * 8) * 128);
    }
  };

  stage(0, 0);
  __syncthreads();   // drains vmcnt+lgkmcnt: tile 0 + Ms staged

  int cur = 0;
  for (int kv0 = 0; kv0 < SEQ; kv0 += 64) {
    if (kv0 + 64 < SEQ) stage(cur ^ 1, kv0 + 64);   // prefetch under compute

    const char* kb_ = (const char*)&Ks[cur][0];
    const char* vb_ = (const char*)&Vts[cur][0];

    // QK^T (swapped): S[kv=16j+rbase+jj][q=fr]
    f32x4 s[4] = {};
#pragma unroll
    for (int ks = 0; ks < 2; ++ks)
#pragma unroll
      for (int j = 0; j < 4; ++j) {
        bf16x8 ak = *(const bf16x8*)(kb_ + (j * 16 + fr) * 128 +
                                     (((ks * 4 + kh) ^ (fr & 7)) * 16));
        s[j] = __builtin_amdgcn_mfma_f32_16x16x32_bf16(ak, bq[ks], s[j], 0, 0, 0);
      }

    // log2-domain online softmax (row q in the 4 kh-lanes)
    float p[16];
    float pmax = -1e30f;
#pragma unroll
    for (int j = 0; j < 4; ++j) {
      float4 mk = *(const float4*)&Ms[kv0 + j * 16 + rbase];
#pragma unroll
      for (int jj = 0; jj < 4; ++jj) {
        float vsc = fmaf(s[j][jj], SSCL, ((const float*)&mk)[jj]);
        p[j * 4 + jj] = vsc;
        pmax = fmaxf(pmax, vsc);
      }
    }
    pmax = fmaxf(pmax, __shfl_xor(pmax, 16));
    pmax = fmaxf(pmax, __shfl_xor(pmax, 32));
    float mnew = fmaxf(m_run, pmax);
    float sc = exp2f(m_run - mnew);
    float rs = 0.f;
#pragma unroll
    for (int t = 0; t < 16; ++t) { p[t] = exp2f(p[t] - mnew); rs += p[t]; }
    rs += __shfl_xor(rs, 16);
    rs += __shfl_xor(rs, 32);
    l_run = l_run * sc + rs;
    m_run = mnew;
#pragma unroll
    for (int db = 0; db < 4; ++db) {
      o[db][0] *= sc; o[db][1] *= sc; o[db][2] *= sc; o[db][3] *= sc;
    }

    // P -> per-wave LDS (bf16), then read as B-frags
#pragma unroll
    for (int j = 0; j < 4; ++j) {
      unsigned int lo = (unsigned)f2bf(p[j * 4 + 0]) | ((unsigned)f2bf(p[j * 4 + 1]) << 16);
      unsigned int hi = (unsigned)f2bf(p[j * 4 + 2]) | ((unsigned)f2bf(p[j * 4 + 3]) << 16);
      unsigned long long pk = (unsigned long long)lo | ((unsigned long long)hi << 32);
      *(unsigned long long*)((char*)Pw + fr * 144 + (j * 16 + rbase) * 2) = pk;
    }
    // PV (swapped): O[d][q] += Vt x P
#pragma unroll
    for (int ks = 0; ks < 2; ++ks) {
      bf16x8 bp = *(const bf16x8*)((char*)Pw + fr * 144 + ks * 64 + kh * 16);
#pragma unroll
      for (int db = 0; db < 4; ++db) {
        bf16x8 av = *(const bf16x8*)(vb_ + (db * 16 + fr) * 128 +
                                     (((ks * 4 + kh) ^ (fr & 7)) * 16));
        o[db] = __builtin_amdgcn_mfma_f32_16x16x32_bf16(av, bp, o[db], 0, 0, 0);
      }
    }

    VMCNT(0);                          // next tile fully staged
    __builtin_amdgcn_s_barrier();      // all waves done reading cur; cur^1 ready
    cur ^= 1;
  }

  float inv = 1.f / l_run;
  const int srow = q0 + w * 16 + fr;
#pragma unroll
  for (int db = 0; db < 4; ++db) {
    ushort4 rb;
    rb.x = f2bf(o[db][0] * inv); rb.y = f2bf(o[db][1] * inv);
    rb.z = f2bf(o[db][2] * inv); rb.w = f2bf(o[db][3] * inv);
    *(ushort4*)(ctxb + ((size_t)(b * SEQ + srow)) * DM + hh * 64 + db * 16 + rbase) = rb;
  }
}

// ---------------- out = LayerNorm(X + Y); optional bf16 copy ----------------
template<int DUAL>
__global__ __launch_bounds__(256)
void add_ln_kernel(const float* __restrict__ X, const float* __restrict__ Y,
                   const float* __restrict__ g, const float* __restrict__ be,
                   float* __restrict__ out, unsigned short* __restrict__ outb)
{
  __shared__ float red[8];
  const int row = blockIdx.x;
  const int tid = threadIdx.x;
  const size_t off = (size_t)row * DM + tid * 4;
  float4 xv = *(const float4*)(X + off);
  float4 yv = *(const float4*)(Y + off);
  float v0 = xv.x + yv.x, v1 = xv.y + yv.y, v2 = xv.z + yv.z, v3 = xv.w + yv.w;
  float s = v0 + v1 + v2 + v3;
#pragma unroll
  for (int m = 1; m < 64; m <<= 1) s += __shfl_xor(s, m);
  if ((tid & 63) == 0) red[tid >> 6] = s;
  __syncthreads();
  float mean = (red[0] + red[1] + red[2] + red[3]) * (1.f / DM);
  float d0 = v0 - mean, d1 = v1 - mean, d2 = v2 - mean, d3 = v3 - mean;
  float sq = d0 * d0 + d1 * d1 + d2 * d2 + d3 * d3;
#pragma unroll
  for (int m = 1; m < 64; m <<= 1) sq += __shfl_xor(sq, m);
  if ((tid & 63) == 0) red[4 + (tid >> 6)] = sq;
  __syncthreads();
  float var = (red[4] + red[5] + red[6] + red[7]) * (1.f / DM);
  float inv = rsqrtf(var + EPSF);
  int col = tid * 4;
  float4 r;
  r.x = d0 * inv * g[col + 0] + be[col + 0];
  r.y = d1 * inv * g[col + 1] + be[col + 1];
  r.z = d2 * inv * g[col + 2] + be[col + 2];
  r.w = d3 * inv * g[col + 3] + be[col + 3];
  *(float4*)(out + off) = r;
  if (DUAL) {
    ushort4 rb;
    rb.x = f2bf(r.x); rb.y = f2bf(r.y); rb.z = f2bf(r.z); rb.w = f2bf(r.w);
    *(ushort4*)(outb + off) = rb;
  }
}

extern "C" void kernel_launch(void* const* d_in, const int* in_sizes, int n_in,
                              void* d_out, int out_size, void* d_ws, size_t ws_size,
                              hipStream_t stream)
{
  const float* x    = (const float*)d_in[0];
  const float* mask = (const float*)d_in[1];
  const float* wq   = (const float*)d_in[2];
  const float* bq   = (const float*)d_in[3];
  const float* wk   = (const float*)d_in[4];
  const float* bk   = (const float*)d_in[5];
  const float* wv   = (const float*)d_in[6];
  const float* bv   = (const float*)d_in[7];
  const float* wo   = (const float*)d_in[8];
  const float* bo   = (const float*)d_in[9];
  const float* w1   = (const float*)d_in[10];
  const float* b1   = (const float*)d_in[11];
  const float* w2   = (const float*)d_in[12];
  const float* b2   = (const float*)d_in[13];
  const float* g1   = (const float*)d_in[14];
  const float* be1  = (const float*)d_in[15];
  const float* g2   = (const float*)d_in[16];
  const float* be2  = (const float*)d_in[17];
  float* out = (float*)d_out;
  char* wsb = (char*)d_ws;

  unsigned short* qb    = (unsigned short*)(wsb);
  unsigned short* kb    = (unsigned short*)(wsb + (16u << 20));
  unsigned short* vtb   = (unsigned short*)(wsb + (32u << 20));
  unsigned short* ctxb  = (unsigned short*)(wsb + (48u << 20));
  unsigned short* xb    = (unsigned short*)(wsb + (64u << 20));
  unsigned short* hbuf  = (unsigned short*)(wsb + (80u << 20));
  unsigned short* wqkvt = (unsigned short*)(wsb + (144u << 20));
  unsigned short* wot   = (unsigned short*)(wsb + (150u << 20));
  unsigned short* w1t   = (unsigned short*)(wsb + (152u << 20));
  unsigned short* w2t   = (unsigned short*)(wsb + (160u << 20));
  float* attn_out = (float*)(wsb);                 // [0,32)  after attention
  float* out1     = (float*)(wsb + (32u << 20));   // [32,64) after WO+LN1
  unsigned short* out1b = xb;                      // [64,80) after LN1
  float* ffn      = (float*)(wsb);                 // [0,32)  after LN1

  dim3 blk(256);
  const int M = BATCH * SEQ;   // 8192

  convert_bf16<<<8192, blk, 0, stream>>>(x, xb, (BATCH * SEQ * DM) / 4);
  transpose_to_bf16<<<dim3(32, 32), blk, 0, stream>>>(wq, wqkvt, DM, DM);
  transpose_to_bf16<<<dim3(32, 32), blk, 0, stream>>>(wk, wqkvt + 1024 * 1024, DM, DM);
  transpose_to_bf16<<<dim3(32, 32), blk, 0, stream>>>(wv, wqkvt + 2 * 1024 * 1024, DM, DM);
  transpose_to_bf16<<<dim3(32, 32), blk, 0, stream>>>(wo, wot, DM, DM);
  transpose_to_bf16<<<dim3(128, 32), blk, 0, stream>>>(w1, w1t, DM, DFF_);
  transpose_to_bf16<<<dim3(32, 128), blk, 0, stream>>>(w2, w2t, DFF_, DM);

  // fused QKV: [8192,1024] @ [3072,1024]^T -> q/k split-head + v transposed (768 blocks)
  gemm128<2><<<dim3((M / 128) * (3072 / 256)), dim3(512), 0, stream>>>(
      xb, wqkvt, bq, bk, bv, nullptr, qb, kb, vtb, M, 3072, DM);

  attn_mfma<<<dim3(SEQ / 64, BATCH * NH), blk, 0, stream>>>(qb, kb, vtb, mask, ctxb);

  // WO: 256 blocks (full fill)
  gemm128<0><<<dim3((M / 128) * (DM / 256)), dim3(512), 0, stream>>>(
      ctxb, wot, bo, nullptr, nullptr, attn_out, nullptr, nullptr, nullptr, M, DM, DM);
  add_ln_kernel<1><<<dim3(M), blk, 0, stream>>>(x, attn_out, g1, be1, out1, out1b);

  // FFN1: 256^2 tile (512 blocks, full fill, best MFMA ratio)
  gemm8<1><<<dim3((M / 256) * (DFF_ / 256)), dim3(512), 0, stream>>>(
      out1b, w1t, b1, nullptr, nullptr, nullptr, hbuf, nullptr, nullptr, M, DFF_, DM);
  // FFN2: 256 blocks (full fill)
  gemm128<0><<<dim3((M / 128) * (DM / 256)), dim3(512), 0, stream>>>(
      hbuf, w2t, b2, nullptr, nullptr, ffn, nullptr, nullptr, nullptr, M, DM, DFF_);

  add_ln_kernel<0><<<dim3(M), blk, 0, stream>>>(out1, ffn, g2, be2, out, nullptr);
}

// Round 9
// 614.403 us; speedup vs baseline: 1.0407x; 1.0407x over previous
//
#include <hip/hip_runtime.h>
#include <hip/hip_bf16.h>
#include <cstdint>

// Transformer encoder layer. bf16-MFMA GEMMs (256² 4-phase + 128x256 2-phase counted-vmcnt
// pipelines) + bf16-MFMA flash attention (single-buffer, 6 blocks/CU, defer-max).
// B=4 S=2048 D=1024 H=16 depth=64 DFF=4096.
//
// Workspace layout (MB offsets, total 168 MB):
//   [0,16)    qb bf16 [B,H,S,64]     -> attn_out fp32 [0,32) -> ffn fp32 [0,32)
//   [16,32)   kb bf16 [B,H,S,64]
//   [32,48)   vtb bf16 [B,H,64,S]    -> out1 fp32 [32,64)
//   [48,64)   ctxb bf16 [B,S,D]
//   [64,80)   xb bf16                -> out1b bf16
//   [80,144)  hbuf bf16 [8192,4096]
//   [144,150) wqkvt bf16 [3072,1024]
//   [150,152) wot bf16 [1024,1024]
//   [152,160) w1t bf16 [4096,1024]
//   [160,168) w2t bf16 [1024,4096]

#define BATCH 4
#define SEQ   2048
#define DM    1024
#define NH    16
#define DEPTH 64
#define DFF_  4096
#define EPSF  1e-6f

typedef short bf16x8 __attribute__((ext_vector_type(8)));
typedef float f32x4  __attribute__((ext_vector_type(4)));

__device__ __forceinline__ unsigned short f2bf(float f) {
  union { float f; unsigned int u; } v; v.f = f;
  unsigned int u = v.u;
  return (unsigned short)((u + 0x7fffu + ((u >> 16) & 1u)) >> 16);  // RNE
}

__device__ __forceinline__ unsigned pkbf(float a, float b) {   // 2 f32 -> packed 2xbf16
  __hip_bfloat162 h = __float22bfloat162_rn(make_float2(a, b));
  unsigned u; __builtin_memcpy(&u, &h, 4); return u;
}

__device__ __forceinline__ void gload_lds16(const void* g, void* l) {
  __builtin_amdgcn_global_load_lds(
      (const __attribute__((address_space(1))) unsigned int*)g,
      (__attribute__((address_space(3))) unsigned int*)l, 16, 0, 0);
}

#define VMCNT(n) asm volatile("s_waitcnt vmcnt(" #n ")" ::: "memory")

// ---------------- 4-phase 256x256 bf16 MFMA GEMM (validated rounds 5-6) ----------------
// Used for FFN1 (M=8192, N=4096: 512 blocks, full fill).
template<int EPI>
__global__ __launch_bounds__(512, 2)
void gemm8(const unsigned short* __restrict__ A, const unsigned short* __restrict__ Bt,
           const float* __restrict__ bias0, const float* __restrict__ bias1,
           const float* __restrict__ bias2, float* __restrict__ Cf,
           unsigned short* __restrict__ Cb0, unsigned short* __restrict__ Cb1,
           unsigned short* __restrict__ Cb2, int M, int N, int K)
{
  __shared__ char smem[131072];
  const int tid  = threadIdx.x;
  const int lane = tid & 63;
  const int wid  = tid >> 6;
  const int wr   = wid >> 2;
  const int wcn  = wid & 3;
  const int fr   = lane & 15;
  const int kh   = lane >> 4;

  const int nbx  = N >> 8;
  const int nwg  = gridDim.x;
  const int flat = blockIdx.x;
  const int swz  = (flat & 7) * (nwg >> 3) + (flat >> 3);
  const int bx = swz % nbx, by = swz / nbx;
  const int m0 = by << 8, n0 = bx << 8;

  const int lr  = tid >> 3;
  const int sch = (tid & 7) ^ (lr & 7);
  const char* gA = (const char*)A + ((size_t)(m0 + lr) * K) * 2 + sch * 16;
  const char* gB = (const char*)Bt + ((size_t)(n0 + lr) * K) * 2 + sch * 16;
  const size_t rstep = (size_t)K * 128;

  const int chk0 = ((kh) ^ (fr & 7)) * 16;
  const int chk1 = ((4 + kh) ^ (fr & 7)) * 16;
  const int rowA = wr * 128 + fr;
  const int rowB = wcn * 64 + fr;

  f32x4 acc[8][4] = {};
  bf16x8 bg[4][2];
  const int NT = K >> 6;

  {
    char* sb = smem;
    gload_lds16(gB + 0 * rstep, sb + 32768 + 0 * 8192 + tid * 16);
    gload_lds16(gB + 1 * rstep, sb + 32768 + 1 * 8192 + tid * 16);
    gload_lds16(gB + 2 * rstep, sb + 32768 + 2 * 8192 + tid * 16);
    gload_lds16(gB + 3 * rstep, sb + 32768 + 3 * 8192 + tid * 16);
    gload_lds16(gA + 0 * rstep, sb + 0 * 8192 + tid * 16);
    gload_lds16(gA + 2 * rstep, sb + 2 * 8192 + tid * 16);
    gload_lds16(gA + 1 * rstep, sb + 1 * 8192 + tid * 16);
    gload_lds16(gA + 3 * rstep, sb + 3 * 8192 + tid * 16);
    VMCNT(2);
    __builtin_amdgcn_s_barrier();
  }

  for (int t = 0; t < NT - 1; ++t) {
    char* rb = smem + ((t & 1) << 16);
    char* sb = smem + (((t + 1) & 1) << 16);
    const size_t kg = (size_t)(t + 1) * 128;
#pragma unroll
    for (int p = 0; p < 4; ++p) {
      if (p == 0) {
        gload_lds16(gB + kg + 0 * rstep, sb + 32768 + 0 * 8192 + tid * 16);
        gload_lds16(gB + kg + 1 * rstep, sb + 32768 + 1 * 8192 + tid * 16);
      } else if (p == 1) {
        gload_lds16(gB + kg + 2 * rstep, sb + 32768 + 2 * 8192 + tid * 16);
        gload_lds16(gB + kg + 3 * rstep, sb + 32768 + 3 * 8192 + tid * 16);
      } else if (p == 2) {
        gload_lds16(gA + kg + 0 * rstep, sb + 0 * 8192 + tid * 16);
        gload_lds16(gA + kg + 2 * rstep, sb + 2 * 8192 + tid * 16);
      } else {
        gload_lds16(gA + kg + 1 * rstep, sb + 1 * 8192 + tid * 16);
        gload_lds16(gA + kg + 3 * rstep, sb + 3 * 8192 + tid * 16);
      }
      if (p == 0) {
#pragma unroll
        for (int j = 0; j < 4; ++j) {
          bg[j][0] = *(const bf16x8*)(rb + 32768 + (rowB + j * 16) * 128 + chk0);
          bg[j][1] = *(const bf16x8*)(rb + 32768 + (rowB + j * 16) * 128 + chk1);
        }
      }
      bf16x8 a00 = *(const bf16x8*)(rb + (rowA + (2 * p) * 16) * 128 + chk0);
      bf16x8 a01 = *(const bf16x8*)(rb + (rowA + (2 * p) * 16) * 128 + chk1);
      bf16x8 a10 = *(const bf16x8*)(rb + (rowA + (2 * p + 1) * 16) * 128 + chk0);
      bf16x8 a11 = *(const bf16x8*)(rb + (rowA + (2 * p + 1) * 16) * 128 + chk1);
      __builtin_amdgcn_s_barrier();
      __builtin_amdgcn_s_setprio(1);
#pragma unroll
      for (int j = 0; j < 4; ++j) {
        acc[2*p][j]   = __builtin_amdgcn_mfma_f32_16x16x32_bf16(a00, bg[j][0], acc[2*p][j], 0, 0, 0);
        acc[2*p][j]   = __builtin_amdgcn_mfma_f32_16x16x32_bf16(a01, bg[j][1], acc[2*p][j], 0, 0, 0);
        acc[2*p+1][j] = __builtin_amdgcn_mfma_f32_16x16x32_bf16(a10, bg[j][0], acc[2*p+1][j], 0, 0, 0);
        acc[2*p+1][j] = __builtin_amdgcn_mfma_f32_16x16x32_bf16(a11, bg[j][1], acc[2*p+1][j], 0, 0, 0);
      }
      __builtin_amdgcn_s_setprio(0);
      if (p == 1) VMCNT(4);
      if (p == 3) VMCNT(2);
      __builtin_amdgcn_s_barrier();
    }
  }
  {
    char* rb = smem + (((NT - 1) & 1) << 16);
#pragma unroll
    for (int p = 0; p < 4; ++p) {
      if (p == 0) {
#pragma unroll
        for (int j = 0; j < 4; ++j) {
          bg[j][0] = *(const bf16x8*)(rb + 32768 + (rowB + j * 16) * 128 + chk0);
          bg[j][1] = *(const bf16x8*)(rb + 32768 + (rowB + j * 16) * 128 + chk1);
        }
      }
      bf16x8 a00 = *(const bf16x8*)(rb + (rowA + (2 * p) * 16) * 128 + chk0);
      bf16x8 a01 = *(const bf16x8*)(rb + (rowA + (2 * p) * 16) * 128 + chk1);
      bf16x8 a10 = *(const bf16x8*)(rb + (rowA + (2 * p + 1) * 16) * 128 + chk0);
      bf16x8 a11 = *(const bf16x8*)(rb + (rowA + (2 * p + 1) * 16) * 128 + chk1);
      __builtin_amdgcn_s_barrier();
      __builtin_amdgcn_s_setprio(1);
#pragma unroll
      for (int j = 0; j < 4; ++j) {
        acc[2*p][j]   = __builtin_amdgcn_mfma_f32_16x16x32_bf16(a00, bg[j][0], acc[2*p][j], 0, 0, 0);
        acc[2*p][j]   = __builtin_amdgcn_mfma_f32_16x16x32_bf16(a01, bg[j][1], acc[2*p][j], 0, 0, 0);
        acc[2*p+1][j] = __builtin_amdgcn_mfma_f32_16x16x32_bf16(a10, bg[j][0], acc[2*p+1][j], 0, 0, 0);
        acc[2*p+1][j] = __builtin_amdgcn_mfma_f32_16x16x32_bf16(a11, bg[j][1], acc[2*p+1][j], 0, 0, 0);
      }
      __builtin_amdgcn_s_setprio(0);
      if (p == 1) VMCNT(0);
      __builtin_amdgcn_s_barrier();
    }
  }

  if (EPI == 2) {
    const int seg = n0 >> 10;
    const float* bp = seg == 0 ? bias0 : (seg == 1 ? bias1 : bias2);
    unsigned short* dst = seg == 0 ? Cb0 : (seg == 1 ? Cb1 : Cb2);
    float bc[4];
#pragma unroll
    for (int j = 0; j < 4; ++j) bc[j] = bp[(n0 & 1023) + wcn * 64 + j * 16 + fr];
#pragma unroll
    for (int m = 0; m < 8; ++m)
#pragma unroll
      for (int jj = 0; jj < 4; ++jj) {
        const int row = m0 + wr * 128 + m * 16 + kh * 4 + jj;
        const int b = row >> 11, s = row & (SEQ - 1);
#pragma unroll
        for (int j = 0; j < 4; ++j) {
          const int cs = (n0 & 1023) + wcn * 64 + j * 16 + fr;
          const int hh = cs >> 6, d = cs & 63;
          const float v = acc[m][j][jj] + bc[j];
          if (seg < 2)
            dst[(((size_t)(b * NH + hh)) * SEQ + s) * DEPTH + d] = f2bf(v);
          else
            dst[(((size_t)(b * NH + hh)) * DEPTH + d) * SEQ + s] = f2bf(v);
        }
      }
  } else {
    float bc[4];
#pragma unroll
    for (int j = 0; j < 4; ++j) bc[j] = bias0[n0 + wcn * 64 + j * 16 + fr];
#pragma unroll
    for (int m = 0; m < 8; ++m)
#pragma unroll
      for (int jj = 0; jj < 4; ++jj) {
        const int row = m0 + wr * 128 + m * 16 + kh * 4 + jj;
#pragma unroll
        for (int j = 0; j < 4; ++j) {
          const int col = n0 + wcn * 64 + j * 16 + fr;
          float v = acc[m][j][jj] + bc[j];
          if (EPI == 1) {
            v = fmaxf(v, 0.f);
            Cb0[(size_t)row * N + col] = f2bf(v);
          } else {
            Cf[(size_t)row * N + col] = v;
          }
        }
      }
  }
}

// ---------------- 2-phase 128x256 bf16 MFMA GEMM ----------------
// 512 thr = 8 waves (1M x 8N); wave tile 128x32 (acc 8x2). BK=64. LDS 2 x 48 KiB.
// 2 phases/K-tile, 16 MFMA per barrier (gemm8 density) at full grid fill for N=1024.
// Regions: B0..B3 (64-row strips), A0 (rows 0..63, read ph0), A1 (rows 64..127, read ph1).
// Stage t+1: ph0 issues B0,B1,B2; ph1 issues B3,A0,A1. FIFO audit: entering ph0(t) only
// A1(t) in flight; ph0 issues 3 -> wait vmcnt(3) retires A1(t) for ph1 reads; ph1 issues
// 3 -> wait vmcnt(1) retires B*(t+1),A0(t+1), leaves A1(t+1). Never drain-0 in loop.
// EPI: 0 = fp32 [M,N] + bias; 2 = fused QKV scatter (q/k split-head, v transposed).
template<int EPI>
__global__ __launch_bounds__(512, 2)
void gemm128(const unsigned short* __restrict__ A, const unsigned short* __restrict__ Bt,
             const float* __restrict__ bias0, const float* __restrict__ bias1,
             const float* __restrict__ bias2, float* __restrict__ Cf,
             unsigned short* __restrict__ Cb0, unsigned short* __restrict__ Cb1,
             unsigned short* __restrict__ Cb2, int M, int N, int K)
{
  __shared__ char smem[98304];
  const int tid  = threadIdx.x;
  const int lane = tid & 63;
  const int wid  = tid >> 6;          // 0..7 = N strip
  const int fr   = lane & 15;
  const int kh   = lane >> 4;

  const int nbx  = N >> 8;
  const int nwg  = gridDim.x;
  const int flat = blockIdx.x;
  const int swz  = (flat & 7) * (nwg >> 3) + (flat >> 3);
  const int bx = swz % nbx, by = swz / nbx;
  const int m0 = by << 7, n0 = bx << 8;

  const int lr  = tid >> 3;
  const int sch = (tid & 7) ^ (lr & 7);
  const char* gA = (const char*)A + ((size_t)(m0 + lr) * K) * 2 + sch * 16;
  const char* gB = (const char*)Bt + ((size_t)(n0 + lr) * K) * 2 + sch * 16;
  const size_t rstep = (size_t)K * 128;

  const int chk0 = ((kh) ^ (fr & 7)) * 16;
  const int chk1 = ((4 + kh) ^ (fr & 7)) * 16;
  const int rowB = wid * 32 + fr;

  f32x4 acc[8][2] = {};
  bf16x8 bg[2][2];
  const int NT = K >> 6;

  // prologue: B0 B1 B2 B3 A0 A1; retire through A0, keep A1 in flight
  {
    char* sb = smem;
    gload_lds16(gB + 0 * rstep, sb + 16384 + 0 * 8192 + tid * 16);
    gload_lds16(gB + 1 * rstep, sb + 16384 + 1 * 8192 + tid * 16);
    gload_lds16(gB + 2 * rstep, sb + 16384 + 2 * 8192 + tid * 16);
    gload_lds16(gB + 3 * rstep, sb + 16384 + 3 * 8192 + tid * 16);
    gload_lds16(gA + 0 * rstep, sb + 0 * 8192 + tid * 16);
    gload_lds16(gA + 1 * rstep, sb + 1 * 8192 + tid * 16);
    VMCNT(1);
    __builtin_amdgcn_s_barrier();
  }

  for (int t = 0; t < NT - 1; ++t) {
    char* rb = smem + (t & 1) * 49152;
    char* sb = smem + ((t + 1) & 1) * 49152;
    const size_t kg = (size_t)(t + 1) * 128;

    // ---- phase 0: A rows 0..63 (m=0..3), all B frags ----
    gload_lds16(gB + kg + 0 * rstep, sb + 16384 + 0 * 8192 + tid * 16);
    gload_lds16(gB + kg + 1 * rstep, sb + 16384 + 1 * 8192 + tid * 16);
    gload_lds16(gB + kg + 2 * rstep, sb + 16384 + 2 * 8192 + tid * 16);
#pragma unroll
    for (int j = 0; j < 2; ++j) {
      bg[j][0] = *(const bf16x8*)(rb + 16384 + (rowB + j * 16) * 128 + chk0);
      bg[j][1] = *(const bf16x8*)(rb + 16384 + (rowB + j * 16) * 128 + chk1);
    }
    {
      bf16x8 a[4][2];
#pragma unroll
      for (int m = 0; m < 4; ++m) {
        a[m][0] = *(const bf16x8*)(rb + ((m * 16 + fr) * 128) + chk0);
        a[m][1] = *(const bf16x8*)(rb + ((m * 16 + fr) * 128) + chk1);
      }
      __builtin_amdgcn_s_barrier();
      __builtin_amdgcn_s_setprio(1);
#pragma unroll
      for (int m = 0; m < 4; ++m)
#pragma unroll
        for (int j = 0; j < 2; ++j) {
          acc[m][j] = __builtin_amdgcn_mfma_f32_16x16x32_bf16(a[m][0], bg[j][0], acc[m][j], 0, 0, 0);
          acc[m][j] = __builtin_amdgcn_mfma_f32_16x16x32_bf16(a[m][1], bg[j][1], acc[m][j], 0, 0, 0);
        }
      __builtin_amdgcn_s_setprio(0);
      VMCNT(3);
      __builtin_amdgcn_s_barrier();
    }

    // ---- phase 1: A rows 64..127 (m=4..7) ----
    gload_lds16(gB + kg + 3 * rstep, sb + 16384 + 3 * 8192 + tid * 16);
    gload_lds16(gA + kg + 0 * rstep, sb + 0 * 8192 + tid * 16);
    gload_lds16(gA + kg + 1 * rstep, sb + 1 * 8192 + tid * 16);
    {
      bf16x8 a[4][2];
#pragma unroll
      for (int m = 0; m < 4; ++m) {
        a[m][0] = *(const bf16x8*)(rb + (((m + 4) * 16 + fr) * 128) + chk0);
        a[m][1] = *(const bf16x8*)(rb + (((m + 4) * 16 + fr) * 128) + chk1);
      }
      __builtin_amdgcn_s_barrier();
      __builtin_amdgcn_s_setprio(1);
#pragma unroll
      for (int m = 0; m < 4; ++m)
#pragma unroll
        for (int j = 0; j < 2; ++j) {
          acc[m+4][j] = __builtin_amdgcn_mfma_f32_16x16x32_bf16(a[m][0], bg[j][0], acc[m+4][j], 0, 0, 0);
          acc[m+4][j] = __builtin_amdgcn_mfma_f32_16x16x32_bf16(a[m][1], bg[j][1], acc[m+4][j], 0, 0, 0);
        }
      __builtin_amdgcn_s_setprio(0);
      VMCNT(1);
      __builtin_amdgcn_s_barrier();
    }
  }
  // final tile: no staging; vmcnt(0) between phases
  {
    char* rb = smem + ((NT - 1) & 1) * 49152;
#pragma unroll
    for (int j = 0; j < 2; ++j) {
      bg[j][0] = *(const bf16x8*)(rb + 16384 + (rowB + j * 16) * 128 + chk0);
      bg[j][1] = *(const bf16x8*)(rb + 16384 + (rowB + j * 16) * 128 + chk1);
    }
    {
      bf16x8 a[4][2];
#pragma unroll
      for (int m = 0; m < 4; ++m) {
        a[m][0] = *(const bf16x8*)(rb + ((m * 16 + fr) * 128) + chk0);
        a[m][1] = *(const bf16x8*)(rb + ((m * 16 + fr) * 128) + chk1);
      }
      __builtin_amdgcn_s_barrier();
      __builtin_amdgcn_s_setprio(1);
#pragma unroll
      for (int m = 0; m < 4; ++m)
#pragma unroll
        for (int j = 0; j < 2; ++j) {
          acc[m][j] = __builtin_amdgcn_mfma_f32_16x16x32_bf16(a[m][0], bg[j][0], acc[m][j], 0, 0, 0);
          acc[m][j] = __builtin_amdgcn_mfma_f32_16x16x32_bf16(a[m][1], bg[j][1], acc[m][j], 0, 0, 0);
        }
      __builtin_amdgcn_s_setprio(0);
      VMCNT(0);
      __builtin_amdgcn_s_barrier();
    }
    {
      bf16x8 a[4][2];
#pragma unroll
      for (int m = 0; m < 4; ++m) {
        a[m][0] = *(const bf16x8*)(rb + (((m + 4) * 16 + fr) * 128) + chk0);
        a[m][1] = *(const bf16x8*)(rb + (((m + 4) * 16 + fr) * 128) + chk1);
      }
#pragma unroll
      for (int m = 0; m < 4; ++m)
#pragma unroll
        for (int j = 0; j < 2; ++j) {
          acc[m+4][j] = __builtin_amdgcn_mfma_f32_16x16x32_bf16(a[m][0], bg[j][0], acc[m+4][j], 0, 0, 0);
          acc[m+4][j] = __builtin_amdgcn_mfma_f32_16x16x32_bf16(a[m][1], bg[j][1], acc[m+4][j], 0, 0, 0);
        }
    }
  }

  if (EPI == 2) {
    const int seg = n0 >> 10;
    const float* bp = seg == 0 ? bias0 : (seg == 1 ? bias1 : bias2);
    unsigned short* dst = seg == 0 ? Cb0 : (seg == 1 ? Cb1 : Cb2);
    float bc[2];
#pragma unroll
    for (int j = 0; j < 2; ++j) bc[j] = bp[(n0 & 1023) + wid * 32 + j * 16 + fr];
#pragma unroll
    for (int m = 0; m < 8; ++m)
#pragma unroll
      for (int jj = 0; jj < 4; ++jj) {
        const int row = m0 + m * 16 + kh * 4 + jj;
        const int b = row >> 11, s = row & (SEQ - 1);
#pragma unroll
        for (int j = 0; j < 2; ++j) {
          const int cs = (n0 & 1023) + wid * 32 + j * 16 + fr;
          const int hh = cs >> 6, d = cs & 63;
          const float v = acc[m][j][jj] + bc[j];
          if (seg < 2)
            dst[(((size_t)(b * NH + hh)) * SEQ + s) * DEPTH + d] = f2bf(v);
          else
            dst[(((size_t)(b * NH + hh)) * DEPTH + d) * SEQ + s] = f2bf(v);
        }
      }
  } else {
    float bc[2];
#pragma unroll
    for (int j = 0; j < 2; ++j) bc[j] = bias0[n0 + wid * 32 + j * 16 + fr];
#pragma unroll
    for (int m = 0; m < 8; ++m)
#pragma unroll
      for (int jj = 0; jj < 4; ++jj) {
        const int row = m0 + m * 16 + kh * 4 + jj;
#pragma unroll
        for (int j = 0; j < 2; ++j) {
          const int col = n0 + wid * 32 + j * 16 + fr;
          Cf[(size_t)row * N + col] = acc[m][j][jj] + bc[j];
        }
      }
  }
}

// ---------------- weight fp32 [K,N] -> bf16 [N,K] transpose ----------------
__global__ __launch_bounds__(256)
void transpose_to_bf16(const float* __restrict__ W, unsigned short* __restrict__ Wt,
                       int K, int N)
{
  __shared__ float t[32][33];
  const int tx = threadIdx.x & 31;
  const int ty = threadIdx.x >> 5;
  const int n0 = blockIdx.x * 32;
  const int k0 = blockIdx.y * 32;
#pragma unroll
  for (int i = 0; i < 4; ++i) {
    int r = ty + i * 8;
    t[r][tx] = W[(size_t)(k0 + r) * N + n0 + tx];
  }
  __syncthreads();
#pragma unroll
  for (int i = 0; i < 4; ++i) {
    int r = ty + i * 8;
    Wt[(size_t)(n0 + r) * K + k0 + tx] = f2bf(t[tx][r]);
  }
}

// ---------------- fp32 -> bf16 elementwise ----------------
__global__ __launch_bounds__(256)
void convert_bf16(const float* __restrict__ X, unsigned short* __restrict__ Xb, int n4)
{
  int i = blockIdx.x * 256 + threadIdx.x;
  if (i < n4) {
    float4 v = ((const float4*)X)[i];
    ushort4 r;
    r.x = f2bf(v.x); r.y = f2bf(v.y); r.z = f2bf(v.z); r.w = f2bf(v.w);
    ((ushort4*)Xb)[i] = r;
  }
}

// ---------------- bf16 MFMA flash attention (single-buffer, high-occupancy) ----------------
// Q,K: [B,H,S,64] bf16; Vt: [B,H,64,S] bf16; ctx out: [B,S,D] bf16.
// Grid (S/64, B*H), 256 thr (4 waves x 16 q-rows). KV tile 64, single-buffered.
// LDS 25.6 KB -> 6 blocks/CU (24 waves): TLP is the latency-hiding mechanism (r6 lesson:
// dbuf's LDS cost beat its pipeline gain). Mask read from global (L2-resident, 32 KB).
// log2-domain softmax; T13 defer-max (skip o-rescale while __all(pmax - m <= 8)).
__global__ __launch_bounds__(256)
void attn_mfma(const unsigned short* __restrict__ Qb, const unsigned short* __restrict__ Kb,
               const unsigned short* __restrict__ Vtb, const float* __restrict__ mask,
               unsigned short* __restrict__ ctxb)
{
  __shared__ unsigned short Ks[64 * 64];
  __shared__ unsigned short Vts[64 * 64];
  __shared__ unsigned short Ps[4][16 * 72];

  const int tid  = threadIdx.x;
  const int w    = tid >> 6;
  const int lane = tid & 63;
  const int fr   = lane & 15;
  const int kh   = lane >> 4;
  const int rbase = kh * 4;
  const int bh = blockIdx.y;
  const int b  = bh >> 4, hh = bh & 15;
  const int q0 = blockIdx.x * 64;

  const float MSCL = -1.0e9f * 1.44269504f;
  const float SSCL = 0.125f * 1.44269504f;

  const size_t qrow = ((size_t)bh * SEQ + q0 + w * 16 + fr) * DEPTH;
  bf16x8 bq[2];
  bq[0] = *(const bf16x8*)(Qb + qrow + kh * 8);
  bq[1] = *(const bf16x8*)(Qb + qrow + 32 + kh * 8);

  float m_run = -1e30f, l_run = 0.f;
  f32x4 o[4] = {};

  const int stg_chunk = (lane & 7) ^ (lane >> 3);
  const int r8 = lane >> 3;
  unsigned short* Pw = &Ps[w][0];
  const float* mrow = mask + (size_t)b * SEQ;

  for (int kv0 = 0; kv0 < SEQ; kv0 += 64) {
    __syncthreads();   // prev-tile readers done
#pragma unroll
    for (int i = 0; i < 2; ++i) {
      int rr = w * 16 + i * 8 + r8;
      gload_lds16((const char*)Kb + (((size_t)bh * SEQ + kv0 + rr) * DEPTH) * 2 + stg_chunk * 16,
                  (char*)Ks + (w * 16 + i * 8) * 128);
      gload_lds16((const char*)Vtb + (((size_t)bh * DEPTH + rr) * SEQ + kv0) * 2 + stg_chunk * 16,
                  (char*)Vts + (w * 16 + i * 8) * 128);
    }
    __syncthreads();   // staging complete (vmcnt drained before barrier)

    // QK^T (swapped): S[kv=16j+rbase+jj][q=fr]
    f32x4 s[4] = {};
    __builtin_amdgcn_s_setprio(1);
#pragma unroll
    for (int ks = 0; ks < 2; ++ks)
#pragma unroll
      for (int j = 0; j < 4; ++j) {
        bf16x8 ak = *(const bf16x8*)((const char*)Ks + (j * 16 + fr) * 128 +
                                     (((ks * 4 + kh) ^ (fr & 7)) * 16));
        s[j] = __builtin_amdgcn_mfma_f32_16x16x32_bf16(ak, bq[ks], s[j], 0, 0, 0);
      }
    __builtin_amdgcn_s_setprio(0);

    // log2-domain online softmax with defer-max
    float p[16];
    float pmax = -1e30f;
#pragma unroll
    for (int j = 0; j < 4; ++j) {
      float4 mk = *(const float4*)&mrow[kv0 + j * 16 + rbase];
#pragma unroll
      for (int jj = 0; jj < 4; ++jj) {
        float vsc = fmaf(((const float*)&mk)[jj], MSCL, s[j][jj] * SSCL);
        p[j * 4 + jj] = vsc;
        pmax = fmaxf(pmax, vsc);
      }
    }
    pmax = fmaxf(pmax, __shfl_xor(pmax, 16));
    pmax = fmaxf(pmax, __shfl_xor(pmax, 32));
    if (!__all(pmax - m_run <= 8.f)) {
      float mnew = fmaxf(m_run, pmax);
      float sc = __builtin_amdgcn_exp2f(m_run - mnew);
      l_run *= sc;
      m_run = mnew;
#pragma unroll
      for (int db = 0; db < 4; ++db) {
        o[db][0] *= sc; o[db][1] *= sc; o[db][2] *= sc; o[db][3] *= sc;
      }
    }
    float rs = 0.f;
#pragma unroll
    for (int t = 0; t < 16; ++t) { p[t] = __builtin_amdgcn_exp2f(p[t] - m_run); rs += p[t]; }
    rs += __shfl_xor(rs, 16);
    rs += __shfl_xor(rs, 32);
    l_run += rs;

    // P -> per-wave LDS (bf16), then read as B-frags
#pragma unroll
    for (int j = 0; j < 4; ++j) {
      unsigned int lo = pkbf(p[j * 4 + 0], p[j * 4 + 1]);
      unsigned int hi = pkbf(p[j * 4 + 2], p[j * 4 + 3]);
      unsigned long long pk = (unsigned long long)lo | ((unsigned long long)hi << 32);
      *(unsigned long long*)((char*)Pw + fr * 144 + (j * 16 + rbase) * 2) = pk;
    }
    // PV (swapped): O[d][q] += Vt x P
    __builtin_amdgcn_s_setprio(1);
#pragma unroll
    for (int ks = 0; ks < 2; ++ks) {
      bf16x8 bp = *(const bf16x8*)((char*)Pw + fr * 144 + ks * 64 + kh * 16);
#pragma unroll
      for (int db = 0; db < 4; ++db) {
        bf16x8 av = *(const bf16x8*)((const char*)Vts + (db * 16 + fr) * 128 +
                                     (((ks * 4 + kh) ^ (fr & 7)) * 16));
        o[db] = __builtin_amdgcn_mfma_f32_16x16x32_bf16(av, bp, o[db], 0, 0, 0);
      }
    }
    __builtin_amdgcn_s_setprio(0);
  }

  float inv = 1.f / l_run;
  const int srow = q0 + w * 16 + fr;
#pragma unroll
  for (int db = 0; db < 4; ++db) {
    ushort4 rb;
    rb.x = f2bf(o[db][0] * inv); rb.y = f2bf(o[db][1] * inv);
    rb.z = f2bf(o[db][2] * inv); rb.w = f2bf(o[db][3] * inv);
    *(ushort4*)(ctxb + ((size_t)(b * SEQ + srow)) * DM + hh * 64 + db * 16 + rbase) = rb;
  }
}

// ---------------- out = LayerNorm(X + Y); optional bf16 copy ----------------
template<int DUAL>
__global__ __launch_bounds__(256)
void add_ln_kernel(const float* __restrict__ X, const float* __restrict__ Y,
                   const float* __restrict__ g, const float* __restrict__ be,
                   float* __restrict__ out, unsigned short* __restrict__ outb)
{
  __shared__ float red[8];
  const int row = blockIdx.x;
  const int tid = threadIdx.x;
  const size_t off = (size_t)row * DM + tid * 4;
  float4 xv = *(const float4*)(X + off);
  float4 yv = *(const float4*)(Y + off);
  float v0 = xv.x + yv.x, v1 = xv.y + yv.y, v2 = xv.z + yv.z, v3 = xv.w + yv.w;
  float s = v0 + v1 + v2 + v3;
#pragma unroll
  for (int m = 1; m < 64; m <<= 1) s += __shfl_xor(s, m);
  if ((tid & 63) == 0) red[tid >> 6] = s;
  __syncthreads();
  float mean = (red[0] + red[1] + red[2] + red[3]) * (1.f / DM);
  float d0 = v0 - mean, d1 = v1 - mean, d2 = v2 - mean, d3 = v3 - mean;
  float sq = d0 * d0 + d1 * d1 + d2 * d2 + d3 * d3;
#pragma unroll
  for (int m = 1; m < 64; m <<= 1) sq += __shfl_xor(sq, m);
  if ((tid & 63) == 0) red[4 + (tid >> 6)] = sq;
  __syncthreads();
  float var = (red[4] + red[5] + red[6] + red[7]) * (1.f / DM);
  float inv = rsqrtf(var + EPSF);
  int col = tid * 4;
  float4 r;
  r.x = d0 * inv * g[col + 0] + be[col + 0];
  r.y = d1 * inv * g[col + 1] + be[col + 1];
  r.z = d2 * inv * g[col + 2] + be[col + 2];
  r.w = d3 * inv * g[col + 3] + be[col + 3];
  *(float4*)(out + off) = r;
  if (DUAL) {
    ushort4 rb;
    rb.x = f2bf(r.x); rb.y = f2bf(r.y); rb.z = f2bf(r.z); rb.w = f2bf(r.w);
    *(ushort4*)(outb + off) = rb;
  }
}

extern "C" void kernel_launch(void* const* d_in, const int* in_sizes, int n_in,
                              void* d_out, int out_size, void* d_ws, size_t ws_size,
                              hipStream_t stream)
{
  const float* x    = (const float*)d_in[0];
  const float* mask = (const float*)d_in[1];
  const float* wq   = (const float*)d_in[2];
  const float* bq   = (const float*)d_in[3];
  const float* wk   = (const float*)d_in[4];
  const float* bk   = (const float*)d_in[5];
  const float* wv   = (const float*)d_in[6];
  const float* bv   = (const float*)d_in[7];
  const float* wo   = (const float*)d_in[8];
  const float* bo   = (const float*)d_in[9];
  const float* w1   = (const float*)d_in[10];
  const float* b1   = (const float*)d_in[11];
  const float* w2   = (const float*)d_in[12];
  const float* b2   = (const float*)d_in[13];
  const float* g1   = (const float*)d_in[14];
  const float* be1  = (const float*)d_in[15];
  const float* g2   = (const float*)d_in[16];
  const float* be2  = (const float*)d_in[17];
  float* out = (float*)d_out;
  char* wsb = (char*)d_ws;

  unsigned short* qb    = (unsigned short*)(wsb);
  unsigned short* kb    = (unsigned short*)(wsb + (16u << 20));
  unsigned short* vtb   = (unsigned short*)(wsb + (32u << 20));
  unsigned short* ctxb  = (unsigned short*)(wsb + (48u << 20));
  unsigned short* xb    = (unsigned short*)(wsb + (64u << 20));
  unsigned short* hbuf  = (unsigned short*)(wsb + (80u << 20));
  unsigned short* wqkvt = (unsigned short*)(wsb + (144u << 20));
  unsigned short* wot   = (unsigned short*)(wsb + (150u << 20));
  unsigned short* w1t   = (unsigned short*)(wsb + (152u << 20));
  unsigned short* w2t   = (unsigned short*)(wsb + (160u << 20));
  float* attn_out = (float*)(wsb);                 // [0,32)  after attention
  float* out1     = (float*)(wsb + (32u << 20));   // [32,64) after WO+LN1
  unsigned short* out1b = xb;                      // [64,80) after LN1
  float* ffn      = (float*)(wsb);                 // [0,32)  after LN1

  dim3 blk(256);
  const int M = BATCH * SEQ;   // 8192

  convert_bf16<<<8192, blk, 0, stream>>>(x, xb, (BATCH * SEQ * DM) / 4);
  transpose_to_bf16<<<dim3(32, 32), blk, 0, stream>>>(wq, wqkvt, DM, DM);
  transpose_to_bf16<<<dim3(32, 32), blk, 0, stream>>>(wk, wqkvt + 1024 * 1024, DM, DM);
  transpose_to_bf16<<<dim3(32, 32), blk, 0, stream>>>(wv, wqkvt + 2 * 1024 * 1024, DM, DM);
  transpose_to_bf16<<<dim3(32, 32), blk, 0, stream>>>(wo, wot, DM, DM);
  transpose_to_bf16<<<dim3(128, 32), blk, 0, stream>>>(w1, w1t, DM, DFF_);
  transpose_to_bf16<<<dim3(32, 128), blk, 0, stream>>>(w2, w2t, DFF_, DM);

  // fused QKV: [8192,1024] @ [3072,1024]^T -> q/k split-head + v transposed (768 blocks)
  gemm128<2><<<dim3((M / 128) * (3072 / 256)), dim3(512), 0, stream>>>(
      xb, wqkvt, bq, bk, bv, nullptr, qb, kb, vtb, M, 3072, DM);

  attn_mfma<<<dim3(SEQ / 64, BATCH * NH), blk, 0, stream>>>(qb, kb, vtb, mask, ctxb);

  // WO: 256 blocks (full fill)
  gemm128<0><<<dim3((M / 128) * (DM / 256)), dim3(512), 0, stream>>>(
      ctxb, wot, bo, nullptr, nullptr, attn_out, nullptr, nullptr, nullptr, M, DM, DM);
  add_ln_kernel<1><<<dim3(M), blk, 0, stream>>>(x, attn_out, g1, be1, out1, out1b);

  // FFN1: 256^2 tile (512 blocks, full fill, best MFMA ratio)
  gemm8<1><<<dim3((M / 256) * (DFF_ / 256)), dim3(512), 0, stream>>>(
      out1b, w1t, b1, nullptr, nullptr, nullptr, hbuf, nullptr, nullptr, M, DFF_, DM);
  // FFN2: 256 blocks (full fill)
  gemm128<0><<<dim3((M / 128) * (DM / 256)), dim3(512), 0, stream>>>(
      hbuf, w2t, b2, nullptr, nullptr, ffn, nullptr, nullptr, nullptr, M, DM, DFF_);

  add_ln_kernel<0><<<dim3(M), blk, 0, stream>>>(out1, ffn, g2, be2, out, nullptr);
}